// Round 3
// baseline (297.843 us; speedup 1.0000x reference)
//
#include <hip/hip_runtime.h>

// NMS + farthest-pair + Voronoi masks, B=131072 heatmaps of 14x14 fp32.
// 4 batches per 64-lane wave (16 lanes = 1 DPP row per batch).
// Argmax = single u32-key max reduction (value<<8 | 255-flat): value-max and
// first-occurrence index in ONE tree+4-step-DPP reduction, pure VALU, no LDS.
// Survivors of (v > 0.6) lie in (0.6,1) -> fp32 exponent fixed at 126, so the
// 23-bit mantissa (+1) preserves exact float ordering in integer compare.
//
// r3: persistent software-pipelined form. 2048 blocks x 4 tiles: loads for
// tile t+1 issue before the ~600-cycle compute chain of tile t (hides HBM
// latency); per-lane xy[]/inv[] tables hoisted out of the tile loop.
// Memory semantics identical to r2 (plain loads/stores, same bytes).

typedef float v4f __attribute__((ext_vector_type(4)));

constexpr int L = 14;
constexpr int NPIX = L * L;   // 196
constexpr int NV4 = NPIX / 4; // 49
constexpr int TPB = 4;        // tiles (of 16 batches) per block

template <int CTRL>
__device__ __forceinline__ unsigned dpp_maxu(unsigned x) {
    unsigned y = (unsigned)__builtin_amdgcn_update_dpp(0, (int)x, CTRL, 0xF, 0xF, true);
    return x > y ? x : y;
}
__device__ __forceinline__ unsigned row_max16u(unsigned x) {
    x = dpp_maxu<0xB1>(x);   // quad_perm xor1
    x = dpp_maxu<0x4E>(x);   // quad_perm xor2
    x = dpp_maxu<0x141>(x);  // row_half_mirror
    x = dpp_maxu<0x140>(x);  // row_mirror
    return x;
}
__device__ __forceinline__ unsigned umax2(unsigned a, unsigned b) { return a > b ? a : b; }
__device__ __forceinline__ unsigned umax3(unsigned a, unsigned b, unsigned c) {
    return umax2(umax2(a, b), c);  // -> v_max3_u32
}

__global__ __launch_bounds__(256) void nms_kernel(const v4f* __restrict__ hm4,
                                                  v4f* __restrict__ out4, int B) {
    const int lane = threadIdx.x & 63;
    const int s = lane & 15;
    const int grp = ((threadIdx.x >> 6) << 2) + (lane >> 4);  // 0..15 in block

    // ---- loop-invariant per-lane tables ----
    int xy[16];        // (x<<8)|y for slot i
    unsigned inv[16];  // 255 - flat  (sentinel flats 196..255 -> inv < 60)
    const int s4 = s << 2;
#pragma unroll
    for (int i = 0; i < 16; ++i) {
        const int fl = s4 + ((i >> 2) << 6) + (i & 3);
        const int x = fl / L, y = fl - (fl / L) * L;
        xy[i] = (x << 8) | y;
        inv[i] = 255u - (unsigned)fl;
    }

    const int tile0 = blockIdx.x * TPB;

    // ---- prologue: load tile 0 ----
    v4f c0, c1, c2, c3 = {0.f, 0.f, 0.f, 0.f};
    {
        const int b = tile0 * 16 + grp;
        if (b < B) {
            const v4f* __restrict__ bp = hm4 + (size_t)b * NV4;
            c0 = bp[s];
            c1 = bp[16 + s];
            c2 = bp[32 + s];
            if (s == 0) c3 = bp[48];
        }
    }

#pragma unroll
    for (int t = 0; t < TPB; ++t) {
        // ---- prefetch tile t+1 (issues before the compute chain) ----
        v4f n0 = {0.f, 0.f, 0.f, 0.f}, n1 = n0, n2 = n0, n3 = n0;
        if (t + 1 < TPB) {
            const int bn = (tile0 + t + 1) * 16 + grp;
            if (bn < B) {
                const v4f* __restrict__ bp = hm4 + (size_t)bn * NV4;
                n0 = bp[s];
                n1 = bp[16 + s];
                n2 = bp[32 + s];
                if (s == 0) n3 = bp[48];
            }
        }

        const int b = (tile0 + t) * 16 + grp;
        if (b < B) {
            // ---- keys: low byte is ALWAYS inv, so "suppress" == key &= 255 ----
            unsigned key[16];
#pragma unroll
            for (int i = 0; i < 16; ++i) {
                const float v = (i < 4) ? c0[i] : (i < 8) ? c1[i - 4]
                              : (i < 12) ? c2[i - 8] : c3[i - 12];
                const unsigned kpos = (((__float_as_uint(v) & 0x7FFFFFu) + 1u) << 8) | inv[i];
                key[i] = (v > 0.6f) ? kpos : inv[i];
            }

            int peaks[4];
#pragma unroll
            for (int r = 0; r < 4; ++r) {
                // balanced tree: 5x max3 over 15 + fold with key[15]
                const unsigned t0 = umax3(key[0], key[1], key[2]);
                const unsigned t1 = umax3(key[3], key[4], key[5]);
                const unsigned t2 = umax3(key[6], key[7], key[8]);
                const unsigned t3 = umax3(key[9], key[10], key[11]);
                const unsigned t4 = umax3(key[12], key[13], key[14]);
                unsigned mk = umax2(umax3(t0, t1, t2), umax3(t3, t4, key[15]));
                mk = row_max16u(mk);
                const int flat = 255 - (int)(mk & 255u);
                peaks[r] = flat;
                if (r < 3) {
                    // window [ax-5, ax+5) x [ay-5, ay+5); clamps never bind for
                    // x,y in [0,13]. Packed test: rr = xy - ((ax-5)*256+(ay-5));
                    // in <=> (rr&255) < 10 AND (unsigned)rr>>8 < 10. A y-borrow
                    // pushes the low byte to [243,255] -> rejected: no FPs.
                    const int ax = flat / L;
                    const int ay = flat - ax * L;
                    const int q = (ax - 5) * 256 + (ay - 5);
#pragma unroll
                    for (int i = 0; i < 16; ++i) {
                        const int rr = xy[i] - q;
                        const bool in = ((rr & 255) < 10) & (((unsigned)rr >> 8) < 10u);
                        key[i] = in ? (key[i] & 255u) : key[i];
                    }
                }
            }

            int cx[4], cy[4];
#pragma unroll
            for (int i = 0; i < 4; ++i) {
                cx[i] = peaks[i] / L;
                cy[i] = peaks[i] - cx[i] * L;
            }

            // farthest pair among 6, first-index-wins argmax
            const int pa[6] = {0, 0, 0, 1, 1, 2};
            const int pb[6] = {1, 2, 3, 2, 3, 3};
            int bestd = -1, ax0 = 0, ay0 = 0, ax1 = 0, ay1 = 0;
#pragma unroll
            for (int p = 0; p < 6; ++p) {
                const int dx = cx[pb[p]] - cx[pa[p]];
                const int dy = cy[pb[p]] - cy[pa[p]];
                const int d = dx * dx + dy * dy;
                if (d > bestd) { bestd = d; ax0 = cx[pa[p]]; ay0 = cy[pa[p]];
                                 ax1 = cx[pb[p]]; ay1 = cy[pb[p]]; }
            }

            // d1<d2 <=> 2(ax1-ax0)x + 2(ay1-ay0)y < (ax1-ax0)(ax0+ax1)+(ay1-ay0)(ay0+ay1)
            const int Ax = (ax1 - ax0) * 2, Ay = (ay1 - ay0) * 2;
            const int K = (ax1 - ax0) * (ax0 + ax1) + (ay1 - ay0) * (ay0 + ay1);

            v4f* __restrict__ o1 = out4 + (size_t)b * NV4;
            v4f* __restrict__ o2 = out4 + (size_t)(B + b) * NV4;
#pragma unroll
            for (int g = 0; g < 4; ++g) {
                v4f mv, nv;
#pragma unroll
                for (int j = 0; j < 4; ++j) {
                    const int i = (g << 2) + j;
                    const int x = xy[i] >> 8, y = xy[i] & 255;
                    const bool tt = (Ax * x + Ay * y) < K;
                    mv[j] = tt ? 1.0f : 0.0f;
                    nv[j] = tt ? 0.0f : 1.0f;
                }
                if (g < 3) {
                    o1[(g << 4) + s] = mv;
                    o2[(g << 4) + s] = nv;
                } else if (s == 0) {
                    o1[48] = mv;
                    o2[48] = nv;
                }
            }
        }

        c0 = n0; c1 = n1; c2 = n2; c3 = n3;
    }
}

extern "C" void kernel_launch(void* const* d_in, const int* in_sizes, int n_in,
                              void* d_out, int out_size, void* d_ws, size_t ws_size,
                              hipStream_t stream) {
    const v4f* hm4 = (const v4f*)d_in[0];
    v4f* out4 = (v4f*)d_out;
    const int B = in_sizes[0] / NPIX;                 // 131072
    const int ntiles = (B + 15) / 16;                 // 8192
    const int blocks = (ntiles + TPB - 1) / TPB;      // 2048
    nms_kernel<<<blocks, 256, 0, stream>>>(hm4, out4, B);
}

// Round 4
// 277.947 us; speedup vs baseline: 1.0716x; 1.0716x over previous
//
#include <hip/hip_runtime.h>

// NMS + farthest-pair + Voronoi masks, B=131072 heatmaps of 14x14 fp32.
// 4 batches per 64-lane wave (16 lanes = 1 DPP row per batch).
// Argmax = single u32-key max reduction (value<<8 | 255-flat): value-max and
// first-occurrence index in ONE tree+4-step-DPP reduction, pure VALU, no LDS.
// Survivors of (v > 0.6) lie in (0.6,1) -> fp32 exponent fixed at 126, so the
// 23-bit mantissa (+1) preserves exact float ordering in integer compare.
//
// r4: DENSE ALIGNED STORES. The per-batch output stride is 784 B (mod 64 =
// 16), so the old per-batch store pattern wrote every 64B line via partial
// segments from multiple instructions -> suspected RMW write amplification
// (~2x write cost; also explains r1's nt-store regression). A wave's 4
// batches are a contiguous 64B-aligned 3136B region per output: store it
// densely (lane l -> region float4 64k+l). Mask values are recomputed at the
// target position from the owning batch's half-plane (Ax,Ay,K), packed into
// one u32 and fetched with a single ds_bpermute. Every output line is now
// written fully by exactly ONE store instruction (incl. the 4-lane tail =
// exactly one aligned 64B line). Loads unchanged from r2.

typedef float v4f __attribute__((ext_vector_type(4)));

constexpr int L = 14;
constexpr int NPIX = L * L;   // 196
constexpr int NV4 = NPIX / 4; // 49

template <int CTRL>
__device__ __forceinline__ unsigned dpp_maxu(unsigned x) {
    unsigned y = (unsigned)__builtin_amdgcn_update_dpp(0, (int)x, CTRL, 0xF, 0xF, true);
    return x > y ? x : y;
}
__device__ __forceinline__ unsigned row_max16u(unsigned x) {
    x = dpp_maxu<0xB1>(x);   // quad_perm xor1
    x = dpp_maxu<0x4E>(x);   // quad_perm xor2
    x = dpp_maxu<0x141>(x);  // row_half_mirror
    x = dpp_maxu<0x140>(x);  // row_mirror
    return x;
}
__device__ __forceinline__ unsigned umax2(unsigned a, unsigned b) { return a > b ? a : b; }
__device__ __forceinline__ unsigned umax3(unsigned a, unsigned b, unsigned c) {
    return umax2(umax2(a, b), c);  // -> v_max3_u32
}

__global__ __launch_bounds__(256) void nms_kernel(const v4f* __restrict__ hm4,
                                                  v4f* __restrict__ out4, int B) {
    const int lane = threadIdx.x & 63;
    const int s = lane & 15;
    const int b0w = blockIdx.x * 16 + ((threadIdx.x >> 6) << 2);  // wave's 1st batch (mult of 4)
    const int b = b0w + (lane >> 4);
    if (b >= B) return;

    const v4f* __restrict__ bp = hm4 + (size_t)b * NV4;
    v4f a0 = bp[s];
    v4f a1 = bp[16 + s];
    v4f a2 = bp[32 + s];
    v4f a3 = {0.f, 0.f, 0.f, 0.f};   // sentinel slots = zero heat
    if (s == 0) a3 = bp[48];

    // flat(slot i) = 4s + 64*(i>>2) + (i&3); sentinel flats 196..255 have
    // inv < 60 so they lose to every real zero-slot (inv >= 60). Low byte of
    // key is ALWAYS inv, so "suppress" == key &= 255.
    unsigned key[16];
    int xy[16];                       // (x<<8)|y
    const int s4 = s << 2;
#pragma unroll
    for (int i = 0; i < 16; ++i) {
        const int fl = s4 + ((i >> 2) << 6) + (i & 3);
        const int x = fl / L, y = fl - (fl / L) * L;
        xy[i] = (x << 8) | y;
        const float v = (i < 4) ? a0[i] : (i < 8) ? a1[i - 4] : (i < 12) ? a2[i - 8] : a3[i - 12];
        const unsigned inv = 255u - (unsigned)fl;
        const unsigned kpos = (((__float_as_uint(v) & 0x7FFFFFu) + 1u) << 8) | inv;
        key[i] = (v > 0.6f) ? kpos : inv;
    }

    int peaks[4];
#pragma unroll
    for (int r = 0; r < 4; ++r) {
        // balanced tree: 5x max3 over 15 + fold with key[15] (8 VALU total)
        const unsigned t0 = umax3(key[0], key[1], key[2]);
        const unsigned t1 = umax3(key[3], key[4], key[5]);
        const unsigned t2 = umax3(key[6], key[7], key[8]);
        const unsigned t3 = umax3(key[9], key[10], key[11]);
        const unsigned t4 = umax3(key[12], key[13], key[14]);
        unsigned mk = umax2(umax3(t0, t1, t2), umax3(t3, t4, key[15]));
        mk = row_max16u(mk);
        const int flat = 255 - (int)(mk & 255u);
        peaks[r] = flat;
        if (r < 3) {
            // window [ax-5, ax+5) x [ay-5, ay+5); clamps never bind for
            // x,y in [0,13]. Packed test: rr = xy - ((ax-5)*256+(ay-5));
            // in <=> (rr&255) < 10 AND (unsigned)rr>>8 < 10. A y-borrow
            // pushes the low byte to [243,255] -> rejected: no FPs.
            const int ax = flat / L;
            const int ay = flat - ax * L;
            const int q = (ax - 5) * 256 + (ay - 5);
#pragma unroll
            for (int i = 0; i < 16; ++i) {
                const int rr = xy[i] - q;
                const bool in = ((rr & 255) < 10) & (((unsigned)rr >> 8) < 10u);
                key[i] = in ? (key[i] & 255u) : key[i];
            }
        }
    }

    int cx[4], cy[4];
#pragma unroll
    for (int i = 0; i < 4; ++i) {
        cx[i] = peaks[i] / L;
        cy[i] = peaks[i] - cx[i] * L;
    }

    // farthest pair among 6, first-index-wins argmax
    const int pa[6] = {0, 0, 0, 1, 1, 2};
    const int pb[6] = {1, 2, 3, 2, 3, 3};
    int bestd = -1, ax0 = 0, ay0 = 0, ax1 = 0, ay1 = 0;
#pragma unroll
    for (int p = 0; p < 6; ++p) {
        const int dx = cx[pb[p]] - cx[pa[p]];
        const int dy = cy[pb[p]] - cy[pa[p]];
        const int d = dx * dx + dy * dy;
        if (d > bestd) { bestd = d; ax0 = cx[pa[p]]; ay0 = cy[pa[p]];
                         ax1 = cx[pb[p]]; ay1 = cy[pb[p]]; }
    }

    // d1 < d2  <=>  2(ax1-ax0)x + 2(ay1-ay0)y < (ax1-ax0)(ax0+ax1)+(ay1-ay0)(ay0+ay1)
    const int Ax = (ax1 - ax0) * 2, Ay = (ay1 - ay0) * 2;   // in [-26,26]
    const int K = (ax1 - ax0) * (ax0 + ax1) + (ay1 - ay0) * (ay0 + ay1);  // in [-676,676]

    // ---- dense aligned epilogue ----
    // Pack the half-plane into one u32: Ax+64 in [38,90] (7b), Ay+64 (7b),
    // K+2048 in [1372,2724] (13b).
    const unsigned P = ((unsigned)(Ax + 64) << 20) | ((unsigned)(Ay + 64) << 13) |
                       (unsigned)(K + 2048);

    // Wave's output regions: contiguous 3136B, 64B-aligned (b0w % 4 == 0,
    // 4*784 = 49*64).
    v4f* __restrict__ o1 = out4 + (size_t)b0w * NV4;
    v4f* __restrict__ o2 = out4 + (size_t)(B + b0w) * NV4;
#pragma unroll
    for (int k = 0; k < 4; ++k) {
        const int j = (k << 6) + lane;          // region float4 index
        const int bb = (j * 669) >> 15;         // j/49, exact for j<=195
        // broadcast owning batch's plane from lane 16*bb (one bpermute)
        const unsigned Pj = (unsigned)__builtin_amdgcn_ds_bpermute(bb << 6, (int)P);
        const int Axj = (int)((Pj >> 20) & 127u) - 64;
        const int Ayj = (int)((Pj >> 13) & 127u) - 64;
        const int Kj  = (int)(Pj & 8191u) - 2048;
        const int f0 = (j - bb * 49) << 2;      // first flat of this float4
        v4f mv, nv;
#pragma unroll
        for (int c = 0; c < 4; ++c) {
            const int fl = f0 + c;              // 0..195
            const int x = (fl * 2341) >> 15;    // fl/14, exact for fl<=195
            const int y = fl - x * L;
            const bool t = (Axj * x + Ayj * y) < Kj;
            mv[c] = t ? 1.0f : 0.0f;
            nv[c] = t ? 0.0f : 1.0f;
        }
        if (j < NPIX) {                          // k<3 always; k==3: lanes 0..3
            o1[j] = mv;                          // one full 64B-line-aligned
            o2[j] = nv;                          // dense store per instruction
        }
    }
}

extern "C" void kernel_launch(void* const* d_in, const int* in_sizes, int n_in,
                              void* d_out, int out_size, void* d_ws, size_t ws_size,
                              hipStream_t stream) {
    const v4f* hm4 = (const v4f*)d_in[0];
    v4f* out4 = (v4f*)d_out;
    const int B = in_sizes[0] / NPIX;        // 131072
    const int blocks = (B + 15) / 16;        // 16 batches per 256-thread block
    nms_kernel<<<blocks, 256, 0, stream>>>(hm4, out4, B);
}